// Round 1
// baseline (1590.159 us; speedup 1.0000x reference)
//
#include <hip/hip_runtime.h>
#include <hip/hip_bf16.h>

#define FEAT 128

// ---------------- degree count ----------------
__global__ void count_kernel(const int* __restrict__ col, int* __restrict__ deg, int E) {
    int e = blockIdx.x * blockDim.x + threadIdx.x;
    if (e < E) atomicAdd(&deg[col[e]], 1);
}

// ---------------- dinv ----------------
__global__ void dinv_kernel(const int* __restrict__ deg, float* __restrict__ dinv, int N) {
    int i = blockIdx.x * blockDim.x + threadIdx.x;
    if (i < N) {
        int d = deg[i];
        dinv[i] = (d > 0) ? rsqrtf((float)d) : 0.0f;
    }
}

// ---------------- exclusive scan (single block, sequential chunks) ----------------
__global__ __launch_bounds__(1024) void scan_kernel(const int* __restrict__ deg, int* __restrict__ offs, int n) {
    __shared__ int sd[1024];
    __shared__ int carry_s;
    int tid = threadIdx.x;
    if (tid == 0) carry_s = 0;
    __syncthreads();
    for (int base = 0; base < n; base += 1024) {
        int i = base + tid;
        int v = (i < n) ? deg[i] : 0;
        sd[tid] = v;
        __syncthreads();
        for (int off = 1; off < 1024; off <<= 1) {
            int t = (tid >= off) ? sd[tid - off] : 0;
            __syncthreads();
            sd[tid] += t;
            __syncthreads();
        }
        int carry = carry_s;
        if (i < n) offs[i] = carry + sd[tid] - v;   // exclusive
        __syncthreads();
        if (tid == 1023) carry_s = carry + sd[1023];
        __syncthreads();
    }
    if (tid == 0) offs[n] = carry_s;
}

// ---------------- CSR fill ----------------
__global__ void fill_kernel(const int* __restrict__ row, const int* __restrict__ col,
                            const float* __restrict__ dinv,
                            const int* __restrict__ offs, int* __restrict__ cursor,
                            int* __restrict__ csr_src, float* __restrict__ csr_w, int E) {
    int e = blockIdx.x * blockDim.x + threadIdx.x;
    if (e < E) {
        int r = row[e];
        int c = col[e];
        int pos = offs[c] + atomicAdd(&cursor[c], 1);
        csr_src[pos] = r;
        csr_w[pos] = dinv[r] * dinv[c];
    }
}

// ---------------- propagation hop: dst[v] = sum_e w_e * src[row_e] ----------------
__global__ __launch_bounds__(FEAT) void prop_kernel(const float* __restrict__ src, float* __restrict__ dst,
                                                    const int* __restrict__ offs,
                                                    const int* __restrict__ csr_src,
                                                    const float* __restrict__ csr_w) {
    int v = blockIdx.x;
    int t = threadIdx.x;
    int s0 = offs[v];
    int s1 = offs[v + 1];
    float acc0 = 0.0f, acc1 = 0.0f;
    int i = s0;
    for (; i + 1 < s1; i += 2) {
        int sa = csr_src[i];
        int sb = csr_src[i + 1];
        float wa = csr_w[i];
        float wb = csr_w[i + 1];
        acc0 = fmaf(wa, src[(size_t)sa * FEAT + t], acc0);
        acc1 = fmaf(wb, src[(size_t)sb * FEAT + t], acc1);
    }
    if (i < s1) {
        int sa = csr_src[i];
        float wa = csr_w[i];
        acc0 = fmaf(wa, src[(size_t)sa * FEAT + t], acc0);
    }
    dst[(size_t)v * FEAT + t] = acc0 + acc1;
}

// ---------------- bias init: acc[v][o] = b[o] ----------------
__global__ void bias_init_kernel(float* __restrict__ acc, const float* __restrict__ b, int total) {
    int i = blockIdx.x * blockDim.x + threadIdx.x;
    if (i < total) acc[i] = b[i & (FEAT - 1)];
}

// ---------------- relu ----------------
__global__ void relu_kernel(float* __restrict__ x, int total) {
    int i = blockIdx.x * blockDim.x + threadIdx.x;
    if (i < total) x[i] = fmaxf(x[i], 0.0f);
}

// ---------------- GEMM accumulate: acc[M,128] += H[M,128] @ W[:, koff:koff+128].T ----------------
// W row-major [128][512]
#define BM 64
__global__ __launch_bounds__(256) void gemm_acc_kernel(const float* __restrict__ H,
                                                       const float* __restrict__ W,
                                                       float* __restrict__ acc,
                                                       int N, int koff) {
    __shared__ float hs[BM][33];     // [row][k], pad 1
    __shared__ float ws[32][132];    // [k][o],   pad 4 (rows 528B, 16B aligned)
    int m0 = blockIdx.x * BM;
    int tid = threadIdx.x;
    int tx = tid & 15;   // col group: cols tx*8..tx*8+7
    int ty = tid >> 4;   // row group: rows ty*4..ty*4+3

    float creg[4][8];
#pragma unroll
    for (int r = 0; r < 4; ++r)
#pragma unroll
        for (int j = 0; j < 8; ++j) creg[r][j] = 0.0f;

    for (int kt = 0; kt < 128; kt += 32) {
        // load H tile: 64 rows x 32 k = 512 float4
#pragma unroll
        for (int j = 0; j < 2; ++j) {
            int q = tid + j * 256;
            int r = q >> 3, c4 = q & 7;
            int rowi = m0 + r;
            float4 v;
            if (rowi < N) v = *(const float4*)(H + (size_t)rowi * FEAT + kt + c4 * 4);
            else { v.x = v.y = v.z = v.w = 0.0f; }
            float* dp = &hs[r][c4 * 4];
            dp[0] = v.x; dp[1] = v.y; dp[2] = v.z; dp[3] = v.w;
        }
        // load W tile transposed: 128 o x 32 k = 1024 float4
#pragma unroll
        for (int j = 0; j < 4; ++j) {
            int q = tid + j * 256;
            int o = q >> 3, c4 = q & 7;
            float4 v = *(const float4*)(W + (size_t)o * 512 + koff + kt + c4 * 4);
            ws[c4 * 4 + 0][o] = v.x;
            ws[c4 * 4 + 1][o] = v.y;
            ws[c4 * 4 + 2][o] = v.z;
            ws[c4 * 4 + 3][o] = v.w;
        }
        __syncthreads();
#pragma unroll
        for (int k = 0; k < 32; ++k) {
            float a0 = hs[ty * 4 + 0][k];
            float a1 = hs[ty * 4 + 1][k];
            float a2 = hs[ty * 4 + 2][k];
            float a3 = hs[ty * 4 + 3][k];
            float4 b0 = *(const float4*)&ws[k][tx * 8];
            float4 b1 = *(const float4*)&ws[k][tx * 8 + 4];
            float bb[8] = {b0.x, b0.y, b0.z, b0.w, b1.x, b1.y, b1.z, b1.w};
#pragma unroll
            for (int j = 0; j < 8; ++j) {
                creg[0][j] = fmaf(a0, bb[j], creg[0][j]);
                creg[1][j] = fmaf(a1, bb[j], creg[1][j]);
                creg[2][j] = fmaf(a2, bb[j], creg[2][j]);
                creg[3][j] = fmaf(a3, bb[j], creg[3][j]);
            }
        }
        __syncthreads();
    }
    // accumulate into acc
#pragma unroll
    for (int r = 0; r < 4; ++r) {
        int rowi = m0 + ty * 4 + r;
        if (rowi < N) {
            float* p = acc + (size_t)rowi * FEAT + tx * 8;
            float4 c0 = *(float4*)p;
            float4 c1 = *(float4*)(p + 4);
            c0.x += creg[r][0]; c0.y += creg[r][1]; c0.z += creg[r][2]; c0.w += creg[r][3];
            c1.x += creg[r][4]; c1.y += creg[r][5]; c1.z += creg[r][6]; c1.w += creg[r][7];
            *(float4*)p = c0;
            *(float4*)(p + 4) = c1;
        }
    }
}

extern "C" void kernel_launch(void* const* d_in, const int* in_sizes, int n_in,
                              void* d_out, int out_size, void* d_ws, size_t ws_size,
                              hipStream_t stream) {
    const float* x   = (const float*)d_in[0];
    const int*   ei  = (const int*)d_in[1];
    const float* W1  = (const float*)d_in[2];
    const float* b1  = (const float*)d_in[3];
    const float* W2  = (const float*)d_in[4];
    const float* b2  = (const float*)d_in[5];
    float* out = (float*)d_out;

    const int N = in_sizes[0] / FEAT;       // 100000
    const int E = in_sizes[1] / 2;          // 1600000
    const int* row = ei;
    const int* col = ei + E;

    // workspace carve
    size_t off = 0;
    auto carve = [&](size_t bytes) -> void* {
        void* p = (char*)d_ws + off;
        off += (bytes + 255) & ~(size_t)255;
        return p;
    };
    int*   deg     = (int*)carve((size_t)N * 4);
    int*   cursor  = (int*)carve((size_t)N * 4);
    float* dinv    = (float*)carve((size_t)N * 4);
    int*   offs    = (int*)carve((size_t)(N + 1) * 4);
    int*   csr_src = (int*)carve((size_t)E * 4);
    float* csr_w   = (float*)carve((size_t)E * 4);
    float* ping    = (float*)carve((size_t)N * FEAT * 4);
    float* pong    = (float*)carve((size_t)N * FEAT * 4);
    float* hbuf    = (float*)carve((size_t)N * FEAT * 4);

    const int total = N * FEAT;
    const int tB = 256;
    const int gE = (E + tB - 1) / tB;
    const int gN = (N + tB - 1) / tB;
    const int gT = (total + tB - 1) / tB;
    const int gG = (N + BM - 1) / BM;

    // ---- norm + CSR build ----
    hipMemsetAsync(deg, 0, (size_t)N * 4, stream);
    hipMemsetAsync(cursor, 0, (size_t)N * 4, stream);
    count_kernel<<<gE, tB, 0, stream>>>(col, deg, E);
    dinv_kernel<<<gN, tB, 0, stream>>>(deg, dinv, N);
    scan_kernel<<<1, 1024, 0, stream>>>(deg, offs, N);
    fill_kernel<<<gE, tB, 0, stream>>>(row, col, dinv, offs, cursor, csr_src, csr_w, E);

    // ---- layer 1: hbuf = relu(concat(x,h1,h2,h3) @ W1.T + b1) ----
    bias_init_kernel<<<gT, tB, 0, stream>>>(hbuf, b1, total);
    gemm_acc_kernel<<<gG, 256, 0, stream>>>(x, W1, hbuf, N, 0);
    prop_kernel<<<N, FEAT, 0, stream>>>(x, ping, offs, csr_src, csr_w);
    gemm_acc_kernel<<<gG, 256, 0, stream>>>(ping, W1, hbuf, N, 128);
    prop_kernel<<<N, FEAT, 0, stream>>>(ping, pong, offs, csr_src, csr_w);
    gemm_acc_kernel<<<gG, 256, 0, stream>>>(pong, W1, hbuf, N, 256);
    prop_kernel<<<N, FEAT, 0, stream>>>(pong, ping, offs, csr_src, csr_w);
    gemm_acc_kernel<<<gG, 256, 0, stream>>>(ping, W1, hbuf, N, 384);
    relu_kernel<<<gT, tB, 0, stream>>>(hbuf, total);

    // ---- layer 2: out = concat(hbuf,h1,h2,h3) @ W2.T + b2 ----
    bias_init_kernel<<<gT, tB, 0, stream>>>(out, b2, total);
    gemm_acc_kernel<<<gG, 256, 0, stream>>>(hbuf, W2, out, N, 0);
    prop_kernel<<<N, FEAT, 0, stream>>>(hbuf, ping, offs, csr_src, csr_w);
    gemm_acc_kernel<<<gG, 256, 0, stream>>>(ping, W2, out, N, 128);
    prop_kernel<<<N, FEAT, 0, stream>>>(ping, pong, offs, csr_src, csr_w);
    gemm_acc_kernel<<<gG, 256, 0, stream>>>(pong, W2, out, N, 256);
    prop_kernel<<<N, FEAT, 0, stream>>>(pong, ping, offs, csr_src, csr_w);
    gemm_acc_kernel<<<gG, 256, 0, stream>>>(ping, W2, out, N, 384);
}

// Round 2
// 1394.670 us; speedup vs baseline: 1.1402x; 1.1402x over previous
//
#include <hip/hip_runtime.h>
#include <hip/hip_bf16.h>

#define FEAT 128
#define SCAN_CHUNK 1024

// ---------------- degree count ----------------
__global__ void count_kernel(const int* __restrict__ col, int* __restrict__ deg, int E) {
    int e = blockIdx.x * blockDim.x + threadIdx.x;
    if (e < E) atomicAdd(&deg[col[e]], 1);
}

// ---------------- dinv ----------------
__global__ void dinv_kernel(const int* __restrict__ deg, float* __restrict__ dinv, int N) {
    int i = blockIdx.x * blockDim.x + threadIdx.x;
    if (i < N) {
        int d = deg[i];
        dinv[i] = (d > 0) ? rsqrtf((float)d) : 0.0f;
    }
}

// ---------------- hierarchical scan ----------------
// A: per-chunk (1024 elems) sums
__global__ __launch_bounds__(256) void scan_partial_kernel(const int* __restrict__ deg,
                                                           int* __restrict__ partials, int n) {
    __shared__ int sd[256];
    int base = blockIdx.x * SCAN_CHUNK;
    int t = threadIdx.x;
    int s = 0;
#pragma unroll
    for (int j = 0; j < 4; ++j) {
        int i = base + t + j * 256;
        if (i < n) s += deg[i];
    }
    sd[t] = s;
    __syncthreads();
    for (int o = 128; o > 0; o >>= 1) {
        if (t < o) sd[t] += sd[t + o];
        __syncthreads();
    }
    if (t == 0) partials[blockIdx.x] = sd[0];
}

// B: single-block exclusive scan of partials (nb <= 1024); writes total to *totalp
__global__ __launch_bounds__(1024) void scan_top_kernel(int* __restrict__ partials, int nb,
                                                        int* __restrict__ totalp) {
    __shared__ int sd[1024];
    int t = threadIdx.x;
    int v = (t < nb) ? partials[t] : 0;
    sd[t] = v;
    __syncthreads();
    for (int o = 1; o < 1024; o <<= 1) {
        int u = (t >= o) ? sd[t - o] : 0;
        __syncthreads();
        sd[t] += u;
        __syncthreads();
    }
    if (t < nb) partials[t] = sd[t] - v;   // exclusive
    if (t == nb - 1) *totalp = sd[t];      // total = E
}

// C: re-scan each chunk with its exclusive block offset
__global__ __launch_bounds__(256) void scan_final_kernel(const int* __restrict__ deg,
                                                         const int* __restrict__ partials,
                                                         int* __restrict__ offs, int n) {
    __shared__ int sums[256];
    __shared__ int blockoff;
    int base = blockIdx.x * SCAN_CHUNK;
    int t = threadIdx.x;
    int v[4];
    int s = 0;
#pragma unroll
    for (int j = 0; j < 4; ++j) {
        int i = base + 4 * t + j;
        v[j] = (i < n) ? deg[i] : 0;
        s += v[j];
    }
    sums[t] = s;
    if (t == 0) blockoff = partials[blockIdx.x];
    __syncthreads();
    int mine = s;
    for (int o = 1; o < 256; o <<= 1) {
        int u = (t >= o) ? sums[t - o] : 0;
        __syncthreads();
        sums[t] += u;
        __syncthreads();
    }
    int ex = sums[t] - mine + blockoff;
#pragma unroll
    for (int j = 0; j < 4; ++j) {
        int i = base + 4 * t + j;
        if (i < n) offs[i] = ex;
        ex += v[j];
    }
}

// ---------------- CSR fill ----------------
__global__ void fill_kernel(const int* __restrict__ row, const int* __restrict__ col,
                            const float* __restrict__ dinv,
                            const int* __restrict__ offs, int* __restrict__ cursor,
                            int* __restrict__ csr_src, float* __restrict__ csr_w, int E) {
    int e = blockIdx.x * blockDim.x + threadIdx.x;
    if (e < E) {
        int r = row[e];
        int c = col[e];
        int pos = offs[c] + atomicAdd(&cursor[c], 1);
        csr_src[pos] = r;
        csr_w[pos] = dinv[r] * dinv[c];
    }
}

// ---------------- propagation hop: dst[v] = sum_e w_e * src[row_e] ----------------
// 4 groups of 32 lanes; each group gathers whole 512B rows via float4.
__global__ __launch_bounds__(128) void prop_kernel(const float* __restrict__ src, float* __restrict__ dst,
                                                   const int* __restrict__ offs,
                                                   const int* __restrict__ csr_src,
                                                   const float* __restrict__ csr_w) {
    int v = blockIdx.x;
    int lane = threadIdx.x & 31;
    int g = threadIdx.x >> 5;
    int s0 = offs[v];
    int s1 = offs[v + 1];
    float4 acc = {0.0f, 0.0f, 0.0f, 0.0f};
    for (int i = s0 + g; i < s1; i += 4) {
        int sa = csr_src[i];
        float wa = csr_w[i];
        float4 xv = ((const float4*)(src + (size_t)sa * FEAT))[lane];
        acc.x = fmaf(wa, xv.x, acc.x);
        acc.y = fmaf(wa, xv.y, acc.y);
        acc.z = fmaf(wa, xv.z, acc.z);
        acc.w = fmaf(wa, xv.w, acc.w);
    }
    __shared__ float4 part[4][32];
    part[g][lane] = acc;
    __syncthreads();
    if (threadIdx.x < 32) {
        float4 a = part[0][threadIdx.x];
        float4 b = part[1][threadIdx.x];
        float4 c = part[2][threadIdx.x];
        float4 d = part[3][threadIdx.x];
        float4 r;
        r.x = (a.x + b.x) + (c.x + d.x);
        r.y = (a.y + b.y) + (c.y + d.y);
        r.z = (a.z + b.z) + (c.z + d.z);
        r.w = (a.w + b.w) + (c.w + d.w);
        ((float4*)(dst + (size_t)v * FEAT))[threadIdx.x] = r;
    }
}

// ---------------- fused GEMM: out[M,128] = concat(H0..H3)[M,512] @ W[128,512].T + b ----------------
// Safe in-place when out aliases H0 (each block reads only its own output rows).
#define BM 64
template <bool RELU>
__global__ __launch_bounds__(256) void gemm4_kernel(const float* __restrict__ H0,
                                                    const float* __restrict__ H1,
                                                    const float* __restrict__ H2,
                                                    const float* __restrict__ H3,
                                                    const float* __restrict__ W,
                                                    const float* __restrict__ bias,
                                                    float* __restrict__ outp, int N) {
    __shared__ float hs[BM][33];     // [row][k]
    __shared__ float ws[32][132];    // [k][o]
    int m0 = blockIdx.x * BM;
    int tid = threadIdx.x;
    int tx = tid & 15;   // cols tx*8..+7
    int ty = tid >> 4;   // rows ty*4..+3

    float creg[4][8];
#pragma unroll
    for (int r = 0; r < 4; ++r)
#pragma unroll
        for (int j = 0; j < 8; ++j) creg[r][j] = 0.0f;

    const float* Hs[4] = {H0, H1, H2, H3};
#pragma unroll
    for (int b = 0; b < 4; ++b) {
        const float* __restrict__ H = Hs[b];
        for (int kt = 0; kt < 128; kt += 32) {
            // H tile: 64 rows x 32 k = 512 float4
#pragma unroll
            for (int j = 0; j < 2; ++j) {
                int q = tid + j * 256;
                int r = q >> 3, c4 = q & 7;
                int rowi = m0 + r;
                float4 v;
                if (rowi < N) v = *(const float4*)(H + (size_t)rowi * FEAT + kt + c4 * 4);
                else { v.x = v.y = v.z = v.w = 0.0f; }
                float* dp = &hs[r][c4 * 4];
                dp[0] = v.x; dp[1] = v.y; dp[2] = v.z; dp[3] = v.w;
            }
            // W tile transposed: 128 o x 32 k
#pragma unroll
            for (int j = 0; j < 4; ++j) {
                int q = tid + j * 256;
                int o = q >> 3, c4 = q & 7;
                float4 v = *(const float4*)(W + (size_t)o * 512 + b * 128 + kt + c4 * 4);
                ws[c4 * 4 + 0][o] = v.x;
                ws[c4 * 4 + 1][o] = v.y;
                ws[c4 * 4 + 2][o] = v.z;
                ws[c4 * 4 + 3][o] = v.w;
            }
            __syncthreads();
#pragma unroll
            for (int k = 0; k < 32; ++k) {
                float a0 = hs[ty * 4 + 0][k];
                float a1 = hs[ty * 4 + 1][k];
                float a2 = hs[ty * 4 + 2][k];
                float a3 = hs[ty * 4 + 3][k];
                float4 b0 = *(const float4*)&ws[k][tx * 8];
                float4 b1 = *(const float4*)&ws[k][tx * 8 + 4];
                float bb[8] = {b0.x, b0.y, b0.z, b0.w, b1.x, b1.y, b1.z, b1.w};
#pragma unroll
                for (int j = 0; j < 8; ++j) {
                    creg[0][j] = fmaf(a0, bb[j], creg[0][j]);
                    creg[1][j] = fmaf(a1, bb[j], creg[1][j]);
                    creg[2][j] = fmaf(a2, bb[j], creg[2][j]);
                    creg[3][j] = fmaf(a3, bb[j], creg[3][j]);
                }
            }
            __syncthreads();
        }
    }
    // epilogue: + bias, optional relu, direct store
    float4 bv0 = *(const float4*)(bias + tx * 8);
    float4 bv1 = *(const float4*)(bias + tx * 8 + 4);
#pragma unroll
    for (int r = 0; r < 4; ++r) {
        int rowi = m0 + ty * 4 + r;
        if (rowi < N) {
            float4 c0, c1;
            c0.x = creg[r][0] + bv0.x; c0.y = creg[r][1] + bv0.y;
            c0.z = creg[r][2] + bv0.z; c0.w = creg[r][3] + bv0.w;
            c1.x = creg[r][4] + bv1.x; c1.y = creg[r][5] + bv1.y;
            c1.z = creg[r][6] + bv1.z; c1.w = creg[r][7] + bv1.w;
            if (RELU) {
                c0.x = fmaxf(c0.x, 0.0f); c0.y = fmaxf(c0.y, 0.0f);
                c0.z = fmaxf(c0.z, 0.0f); c0.w = fmaxf(c0.w, 0.0f);
                c1.x = fmaxf(c1.x, 0.0f); c1.y = fmaxf(c1.y, 0.0f);
                c1.z = fmaxf(c1.z, 0.0f); c1.w = fmaxf(c1.w, 0.0f);
            }
            float* p = outp + (size_t)rowi * FEAT + tx * 8;
            *(float4*)p = c0;
            *(float4*)(p + 4) = c1;
        }
    }
}

extern "C" void kernel_launch(void* const* d_in, const int* in_sizes, int n_in,
                              void* d_out, int out_size, void* d_ws, size_t ws_size,
                              hipStream_t stream) {
    const float* x   = (const float*)d_in[0];
    const int*   ei  = (const int*)d_in[1];
    const float* W1  = (const float*)d_in[2];
    const float* b1  = (const float*)d_in[3];
    const float* W2  = (const float*)d_in[4];
    const float* b2  = (const float*)d_in[5];
    float* out = (float*)d_out;

    const int N = in_sizes[0] / FEAT;       // 100000
    const int E = in_sizes[1] / 2;          // 1600000
    const int* row = ei;
    const int* col = ei + E;
    const int nb = (N + SCAN_CHUNK - 1) / SCAN_CHUNK;   // 98

    // workspace carve
    size_t off = 0;
    auto carve = [&](size_t bytes) -> void* {
        void* p = (char*)d_ws + off;
        off += (bytes + 255) & ~(size_t)255;
        return p;
    };
    int*   deg      = (int*)carve((size_t)N * 4);
    int*   cursor   = (int*)carve((size_t)N * 4);
    float* dinv     = (float*)carve((size_t)N * 4);
    int*   offs     = (int*)carve((size_t)(N + 1) * 4);
    int*   partials = (int*)carve((size_t)nb * 4);
    int*   csr_src  = (int*)carve((size_t)E * 4);
    float* csr_w    = (float*)carve((size_t)E * 4);
    float* t1       = (float*)carve((size_t)N * FEAT * 4);
    float* t2       = (float*)carve((size_t)N * FEAT * 4);
    float* t3       = (float*)carve((size_t)N * FEAT * 4);

    const int tB = 256;
    const int gE = (E + tB - 1) / tB;
    const int gN = (N + tB - 1) / tB;
    const int gG = (N + BM - 1) / BM;

    // ---- norm + CSR build ----
    hipMemsetAsync(deg, 0, (size_t)N * 4, stream);
    hipMemsetAsync(cursor, 0, (size_t)N * 4, stream);
    count_kernel<<<gE, tB, 0, stream>>>(col, deg, E);
    dinv_kernel<<<gN, tB, 0, stream>>>(deg, dinv, N);
    scan_partial_kernel<<<nb, 256, 0, stream>>>(deg, partials, N);
    scan_top_kernel<<<1, 1024, 0, stream>>>(partials, nb, offs + N);
    scan_final_kernel<<<nb, 256, 0, stream>>>(deg, partials, offs, N);
    fill_kernel<<<gE, tB, 0, stream>>>(row, col, dinv, offs, cursor, csr_src, csr_w, E);

    // ---- layer 1: out = relu(concat(x,h1,h2,h3) @ W1.T + b1) ----
    prop_kernel<<<N, 128, 0, stream>>>(x, t1, offs, csr_src, csr_w);
    prop_kernel<<<N, 128, 0, stream>>>(t1, t2, offs, csr_src, csr_w);
    prop_kernel<<<N, 128, 0, stream>>>(t2, t3, offs, csr_src, csr_w);
    gemm4_kernel<true><<<gG, 256, 0, stream>>>(x, t1, t2, t3, W1, b1, out, N);

    // ---- layer 2: out = concat(out,h1,h2,h3) @ W2.T + b2 (in-place safe) ----
    prop_kernel<<<N, 128, 0, stream>>>(out, t1, offs, csr_src, csr_w);
    prop_kernel<<<N, 128, 0, stream>>>(t1, t2, offs, csr_src, csr_w);
    prop_kernel<<<N, 128, 0, stream>>>(t2, t3, offs, csr_src, csr_w);
    gemm4_kernel<false><<<gG, 256, 0, stream>>>(out, t1, t2, t3, W2, b2, out, N);
}

// Round 3
// 665.954 us; speedup vs baseline: 2.3878x; 2.0942x over previous
//
#include <hip/hip_runtime.h>
#include <hip/hip_fp16.h>

#define FEAT 128
#define SCAN_CHUNK 1024

typedef _Float16 half_t;
typedef _Float16 half4 __attribute__((ext_vector_type(4)));
typedef _Float16 half8 __attribute__((ext_vector_type(8)));
typedef float float4v __attribute__((ext_vector_type(4)));

// ---------------- degree count ----------------
__global__ void count_kernel(const int* __restrict__ col, int* __restrict__ deg, int E) {
    int e = blockIdx.x * blockDim.x + threadIdx.x;
    if (e < E) atomicAdd(&deg[col[e]], 1);
}

// ---------------- dinv ----------------
__global__ void dinv_kernel(const int* __restrict__ deg, float* __restrict__ dinv, int N) {
    int i = blockIdx.x * blockDim.x + threadIdx.x;
    if (i < N) {
        int d = deg[i];
        dinv[i] = (d > 0) ? rsqrtf((float)d) : 0.0f;
    }
}

// ---------------- hierarchical scan ----------------
__global__ __launch_bounds__(256) void scan_partial_kernel(const int* __restrict__ deg,
                                                           int* __restrict__ partials, int n) {
    __shared__ int sd[256];
    int base = blockIdx.x * SCAN_CHUNK;
    int t = threadIdx.x;
    int s = 0;
#pragma unroll
    for (int j = 0; j < 4; ++j) {
        int i = base + t + j * 256;
        if (i < n) s += deg[i];
    }
    sd[t] = s;
    __syncthreads();
    for (int o = 128; o > 0; o >>= 1) {
        if (t < o) sd[t] += sd[t + o];
        __syncthreads();
    }
    if (t == 0) partials[blockIdx.x] = sd[0];
}

__global__ __launch_bounds__(1024) void scan_top_kernel(int* __restrict__ partials, int nb,
                                                        int* __restrict__ totalp) {
    __shared__ int sd[1024];
    int t = threadIdx.x;
    int v = (t < nb) ? partials[t] : 0;
    sd[t] = v;
    __syncthreads();
    for (int o = 1; o < 1024; o <<= 1) {
        int u = (t >= o) ? sd[t - o] : 0;
        __syncthreads();
        sd[t] += u;
        __syncthreads();
    }
    if (t < nb) partials[t] = sd[t] - v;   // exclusive
    if (t == nb - 1) *totalp = sd[t];      // total = E
}

__global__ __launch_bounds__(256) void scan_final_kernel(const int* __restrict__ deg,
                                                         const int* __restrict__ partials,
                                                         int* __restrict__ offs, int n) {
    __shared__ int sums[256];
    __shared__ int blockoff;
    int base = blockIdx.x * SCAN_CHUNK;
    int t = threadIdx.x;
    int v[4];
    int s = 0;
#pragma unroll
    for (int j = 0; j < 4; ++j) {
        int i = base + 4 * t + j;
        v[j] = (i < n) ? deg[i] : 0;
        s += v[j];
    }
    sums[t] = s;
    if (t == 0) blockoff = partials[blockIdx.x];
    __syncthreads();
    int mine = s;
    for (int o = 1; o < 256; o <<= 1) {
        int u = (t >= o) ? sums[t - o] : 0;
        __syncthreads();
        sums[t] += u;
        __syncthreads();
    }
    int ex = sums[t] - mine + blockoff;
#pragma unroll
    for (int j = 0; j < 4; ++j) {
        int i = base + 4 * t + j;
        if (i < n) offs[i] = ex;
        ex += v[j];
    }
}

// ---------------- CSR fill ----------------
__global__ void fill_kernel(const int* __restrict__ row, const int* __restrict__ col,
                            const float* __restrict__ dinv,
                            const int* __restrict__ offs, int* __restrict__ cursor,
                            int* __restrict__ csr_src, float* __restrict__ csr_w, int E) {
    int e = blockIdx.x * blockDim.x + threadIdx.x;
    if (e < E) {
        int r = row[e];
        int c = col[e];
        int pos = offs[c] + atomicAdd(&cursor[c], 1);
        csr_src[pos] = r;
        csr_w[pos] = dinv[r] * dinv[c];
    }
}

// ---------------- fp32 -> fp16 convert (float4 per thread) ----------------
__global__ void f2h_kernel(const float* __restrict__ in, half_t* __restrict__ out, int total4) {
    int i = blockIdx.x * blockDim.x + threadIdx.x;
    if (i < total4) {
        float4 v = ((const float4*)in)[i];
        half4 o;
        o.x = (half_t)v.x; o.y = (half_t)v.y; o.z = (half_t)v.z; o.w = (half_t)v.w;
        ((half4*)out)[i] = o;
    }
}

// ---------------- fp16 propagation hop: dst[v] = sum_e w_e * src[row_e] ----------------
// 32-lane group owns one node; lane reads 8B (4 halfs) of the 256B row.
__global__ __launch_bounds__(128) void prop16_kernel(const half_t* __restrict__ src,
                                                     half_t* __restrict__ dst,
                                                     const int* __restrict__ offs,
                                                     const int* __restrict__ csr_src,
                                                     const float* __restrict__ csr_w, int N) {
    int v = blockIdx.x * 4 + (threadIdx.x >> 5);
    if (v >= N) return;
    int lane = threadIdx.x & 31;
    int s0 = offs[v];
    int s1 = offs[v + 1];
    float4v acc0 = (float4v)0.0f, acc1 = (float4v)0.0f;
    int i = s0;
    for (; i + 1 < s1; i += 2) {
        int sa = csr_src[i];
        int sb = csr_src[i + 1];
        float wa = csr_w[i];
        float wb = csr_w[i + 1];
        half4 va = *(const half4*)(src + (size_t)sa * FEAT + lane * 4);
        half4 vb = *(const half4*)(src + (size_t)sb * FEAT + lane * 4);
        acc0.x = fmaf(wa, (float)va.x, acc0.x);
        acc0.y = fmaf(wa, (float)va.y, acc0.y);
        acc0.z = fmaf(wa, (float)va.z, acc0.z);
        acc0.w = fmaf(wa, (float)va.w, acc0.w);
        acc1.x = fmaf(wb, (float)vb.x, acc1.x);
        acc1.y = fmaf(wb, (float)vb.y, acc1.y);
        acc1.z = fmaf(wb, (float)vb.z, acc1.z);
        acc1.w = fmaf(wb, (float)vb.w, acc1.w);
    }
    if (i < s1) {
        int sa = csr_src[i];
        float wa = csr_w[i];
        half4 va = *(const half4*)(src + (size_t)sa * FEAT + lane * 4);
        acc0.x = fmaf(wa, (float)va.x, acc0.x);
        acc0.y = fmaf(wa, (float)va.y, acc0.y);
        acc0.z = fmaf(wa, (float)va.z, acc0.z);
        acc0.w = fmaf(wa, (float)va.w, acc0.w);
    }
    half4 o;
    o.x = (half_t)(acc0.x + acc1.x);
    o.y = (half_t)(acc0.y + acc1.y);
    o.z = (half_t)(acc0.z + acc1.z);
    o.w = (half_t)(acc0.w + acc1.w);
    *(half4*)(dst + (size_t)v * FEAT + lane * 4) = o;
}

// ---------------- MFMA GEMM: out[M,128] = concat(H0..H3)[M,512] @ W[128,512].T + b ----------------
// Block: 256 threads = 4 waves; wave w owns rows m0..m0+15; computes all 128 out cols.
// A-frag = W tile (16 o x 32 k) from LDS; B-frag = H^T tile (32 k x 16 m) direct 16B global load.
// D[o][m]: lane holds D[(lane>>4)*4+r][lane&15] -> 4 consecutive o per lane -> coalesced-ish stores.
template <bool RELU, bool HALFOUT>
__global__ __launch_bounds__(256) void gemm16_kernel(const half_t* __restrict__ H0,
                                                     const half_t* __restrict__ H1,
                                                     const half_t* __restrict__ H2,
                                                     const half_t* __restrict__ H3,
                                                     const half_t* __restrict__ W,   // [128][512] fp16
                                                     const float* __restrict__ bias, // [128] fp32
                                                     half_t* __restrict__ out_h,
                                                     float* __restrict__ out_f, int N) {
    __shared__ half_t ws[128][40];   // [o][k-slice 32, pad->40] : 10 KB
    const int tid = threadIdx.x;
    const int lane = tid & 63;
    const int wid = tid >> 6;
    const int lr = lane & 15;        // m-in-tile
    const int lk = lane >> 4;        // 0..3
    const int m = blockIdx.x * 64 + wid * 16 + lr;
    const bool mok = (m < N);

    float4v acc[8];
#pragma unroll
    for (int ct = 0; ct < 8; ++ct) acc[ct] = (float4v)0.0f;

    const half_t* Hs[4] = {H0, H1, H2, H3};
    const int wo = tid >> 1;         // 0..127 : o row staged by this thread
    const int wh = tid & 1;          // 16-half chunk

#pragma unroll
    for (int b = 0; b < 4; ++b) {
        const half_t* __restrict__ H = Hs[b];
#pragma unroll
        for (int kt = 0; kt < 128; kt += 32) {
            // issue B-frag global load early (overlaps staging + barriers)
            half8 hfrag = (half8)(half_t)0.0f;
            if (mok) hfrag = *(const half8*)(H + (size_t)m * FEAT + kt + lk * 8);
            // stage W k-slice: [128 o][32 k] = 8 KB
            const half8* wsrc = (const half8*)(W + (size_t)wo * 512 + b * 128 + kt + wh * 16);
            half8 w0 = wsrc[0];
            half8 w1 = wsrc[1];
            __syncthreads();   // prior iteration's ds_reads done
            *(half8*)&ws[wo][wh * 16 + 0] = w0;
            *(half8*)&ws[wo][wh * 16 + 8] = w1;
            __syncthreads();
#pragma unroll
            for (int ct = 0; ct < 8; ++ct) {
                half8 wfrag = *(const half8*)&ws[ct * 16 + lr][lk * 8];
                acc[ct] = __builtin_amdgcn_mfma_f32_16x16x32_f16(wfrag, hfrag, acc[ct], 0, 0, 0);
            }
        }
    }

    if (mok) {
#pragma unroll
        for (int ct = 0; ct < 8; ++ct) {
            int o = ct * 16 + lk * 4;
            float4 bv = *(const float4*)(bias + o);
            float r0 = acc[ct][0] + bv.x;
            float r1 = acc[ct][1] + bv.y;
            float r2 = acc[ct][2] + bv.z;
            float r3 = acc[ct][3] + bv.w;
            if (RELU) {
                r0 = fmaxf(r0, 0.0f); r1 = fmaxf(r1, 0.0f);
                r2 = fmaxf(r2, 0.0f); r3 = fmaxf(r3, 0.0f);
            }
            if (HALFOUT) {
                half4 hv;
                hv.x = (half_t)r0; hv.y = (half_t)r1; hv.z = (half_t)r2; hv.w = (half_t)r3;
                *(half4*)(out_h + (size_t)m * FEAT + o) = hv;
            } else {
                float4 fv;
                fv.x = r0; fv.y = r1; fv.z = r2; fv.w = r3;
                *(float4*)(out_f + (size_t)m * FEAT + o) = fv;
            }
        }
    }
}

extern "C" void kernel_launch(void* const* d_in, const int* in_sizes, int n_in,
                              void* d_out, int out_size, void* d_ws, size_t ws_size,
                              hipStream_t stream) {
    const float* x   = (const float*)d_in[0];
    const int*   ei  = (const int*)d_in[1];
    const float* W1  = (const float*)d_in[2];
    const float* b1  = (const float*)d_in[3];
    const float* W2  = (const float*)d_in[4];
    const float* b2  = (const float*)d_in[5];
    float* out = (float*)d_out;

    const int N = in_sizes[0] / FEAT;       // 100000
    const int E = in_sizes[1] / 2;          // 1600000
    const int* row = ei;
    const int* col = ei + E;
    const int nb = (N + SCAN_CHUNK - 1) / SCAN_CHUNK;

    // workspace carve
    size_t off = 0;
    auto carve = [&](size_t bytes) -> void* {
        void* p = (char*)d_ws + off;
        off += (bytes + 255) & ~(size_t)255;
        return p;
    };
    int*    deg      = (int*)carve((size_t)N * 4);
    int*    cursor   = (int*)carve((size_t)N * 4);
    float*  dinv     = (float*)carve((size_t)N * 4);
    int*    offs     = (int*)carve((size_t)(N + 1) * 4);
    int*    partials = (int*)carve((size_t)nb * 4);
    int*    csr_src  = (int*)carve((size_t)E * 4);
    float*  csr_w    = (float*)carve((size_t)E * 4);
    half_t* x16      = (half_t*)carve((size_t)N * FEAT * 2);
    half_t* t1       = (half_t*)carve((size_t)N * FEAT * 2);
    half_t* t2       = (half_t*)carve((size_t)N * FEAT * 2);
    half_t* t3       = (half_t*)carve((size_t)N * FEAT * 2);
    half_t* hbuf     = (half_t*)carve((size_t)N * FEAT * 2);
    half_t* w1h      = (half_t*)carve((size_t)FEAT * 512 * 2);
    half_t* w2h      = (half_t*)carve((size_t)FEAT * 512 * 2);

    const int tB = 256;
    const int gE = (E + tB - 1) / tB;
    const int gN = (N + tB - 1) / tB;
    const int gP = (N + 3) / 4;                 // prop16 blocks (4 nodes/block)
    const int gG = (N + 63) / 64;               // gemm16 blocks (64 rows/block)
    const int xt4 = N * FEAT / 4;
    const int wt4 = FEAT * 512 / 4;

    // ---- norm + CSR build ----
    hipMemsetAsync(deg, 0, (size_t)N * 4, stream);
    hipMemsetAsync(cursor, 0, (size_t)N * 4, stream);
    count_kernel<<<gE, tB, 0, stream>>>(col, deg, E);
    dinv_kernel<<<gN, tB, 0, stream>>>(deg, dinv, N);
    scan_partial_kernel<<<nb, 256, 0, stream>>>(deg, partials, N);
    scan_top_kernel<<<1, 1024, 0, stream>>>(partials, nb, offs + N);
    scan_final_kernel<<<nb, 256, 0, stream>>>(deg, partials, offs, N);
    fill_kernel<<<gE, tB, 0, stream>>>(row, col, dinv, offs, cursor, csr_src, csr_w, E);

    // ---- fp16 conversions ----
    f2h_kernel<<<(xt4 + tB - 1) / tB, tB, 0, stream>>>(x, x16, xt4);
    f2h_kernel<<<(wt4 + tB - 1) / tB, tB, 0, stream>>>(W1, w1h, wt4);
    f2h_kernel<<<(wt4 + tB - 1) / tB, tB, 0, stream>>>(W2, w2h, wt4);

    // ---- layer 1: hbuf = relu(concat(x,h1,h2,h3) @ W1.T + b1)  (fp16) ----
    prop16_kernel<<<gP, 128, 0, stream>>>(x16, t1, offs, csr_src, csr_w, N);
    prop16_kernel<<<gP, 128, 0, stream>>>(t1, t2, offs, csr_src, csr_w, N);
    prop16_kernel<<<gP, 128, 0, stream>>>(t2, t3, offs, csr_src, csr_w, N);
    gemm16_kernel<true, true><<<gG, 256, 0, stream>>>(x16, t1, t2, t3, w1h, b1, hbuf, nullptr, N);

    // ---- layer 2: out = concat(hbuf,h1,h2,h3) @ W2.T + b2  (fp32 out) ----
    prop16_kernel<<<gP, 128, 0, stream>>>(hbuf, t1, offs, csr_src, csr_w, N);
    prop16_kernel<<<gP, 128, 0, stream>>>(t1, t2, offs, csr_src, csr_w, N);
    prop16_kernel<<<gP, 128, 0, stream>>>(t2, t3, offs, csr_src, csr_w, N);
    gemm16_kernel<false, false><<<gG, 256, 0, stream>>>(hbuf, t1, t2, t3, w2h, b2, nullptr, out, N);
}

// Round 4
// 617.407 us; speedup vs baseline: 2.5755x; 1.0786x over previous
//
#include <hip/hip_runtime.h>
#include <hip/hip_fp16.h>

#define FEAT 128
#define SCAN_CHUNK 1024

typedef _Float16 half_t;
typedef _Float16 half4 __attribute__((ext_vector_type(4)));
typedef _Float16 half8 __attribute__((ext_vector_type(8)));
typedef float float4v __attribute__((ext_vector_type(4)));

// ---------------- degree count ----------------
__global__ void count_kernel(const int* __restrict__ col, int* __restrict__ deg, int E) {
    int e = blockIdx.x * blockDim.x + threadIdx.x;
    if (e < E) atomicAdd(&deg[col[e]], 1);
}

// ---------------- hierarchical scan ----------------
__global__ __launch_bounds__(256) void scan_partial_kernel(const int* __restrict__ deg,
                                                           int* __restrict__ partials, int n) {
    __shared__ int sd[256];
    int base = blockIdx.x * SCAN_CHUNK;
    int t = threadIdx.x;
    int s = 0;
#pragma unroll
    for (int j = 0; j < 4; ++j) {
        int i = base + t + j * 256;
        if (i < n) s += deg[i];
    }
    sd[t] = s;
    __syncthreads();
    for (int o = 128; o > 0; o >>= 1) {
        if (t < o) sd[t] += sd[t + o];
        __syncthreads();
    }
    if (t == 0) partials[blockIdx.x] = sd[0];
}

__global__ __launch_bounds__(1024) void scan_top_kernel(int* __restrict__ partials, int nb,
                                                        int* __restrict__ totalp) {
    __shared__ int sd[1024];
    int t = threadIdx.x;
    int v = (t < nb) ? partials[t] : 0;
    sd[t] = v;
    __syncthreads();
    for (int o = 1; o < 1024; o <<= 1) {
        int u = (t >= o) ? sd[t - o] : 0;
        __syncthreads();
        sd[t] += u;
        __syncthreads();
    }
    if (t < nb) partials[t] = sd[t] - v;   // exclusive
    if (t == nb - 1) *totalp = sd[t];      // total = E
}

// C: re-scan each chunk; also emits dinv (fused)
__global__ __launch_bounds__(256) void scan_final_kernel(const int* __restrict__ deg,
                                                         const int* __restrict__ partials,
                                                         int* __restrict__ offs,
                                                         float* __restrict__ dinv, int n) {
    __shared__ int sums[256];
    __shared__ int blockoff;
    int base = blockIdx.x * SCAN_CHUNK;
    int t = threadIdx.x;
    int v[4];
    int s = 0;
#pragma unroll
    for (int j = 0; j < 4; ++j) {
        int i = base + 4 * t + j;
        v[j] = (i < n) ? deg[i] : 0;
        s += v[j];
    }
    sums[t] = s;
    if (t == 0) blockoff = partials[blockIdx.x];
    __syncthreads();
    int mine = s;
    for (int o = 1; o < 256; o <<= 1) {
        int u = (t >= o) ? sums[t - o] : 0;
        __syncthreads();
        sums[t] += u;
        __syncthreads();
    }
    int ex = sums[t] - mine + blockoff;
#pragma unroll
    for (int j = 0; j < 4; ++j) {
        int i = base + 4 * t + j;
        if (i < n) {
            offs[i] = ex;
            dinv[i] = (v[j] > 0) ? rsqrtf((float)v[j]) : 0.0f;
        }
        ex += v[j];
    }
}

// ---------------- CSR fill: packed 8B {src, w} per edge ----------------
// cursor must be pre-loaded with offs (d2d copy).
__global__ void fill_kernel(const int* __restrict__ row, const int* __restrict__ col,
                            const float* __restrict__ dinv,
                            int* __restrict__ cursor,
                            int2* __restrict__ csr, int E) {
    int e = blockIdx.x * blockDim.x + threadIdx.x;
    if (e < E) {
        int r = row[e];
        int c = col[e];
        int pos = atomicAdd(&cursor[c], 1);
        float w = dinv[r] * dinv[c];
        int2 pk;
        pk.x = r;
        pk.y = __float_as_int(w);
        csr[pos] = pk;
    }
}

// ---------------- fused fp32->fp16 convert for x, W1, W2 ----------------
__global__ void f2h3_kernel(const float* __restrict__ a, half_t* __restrict__ ah, int na4,
                            const float* __restrict__ b, half_t* __restrict__ bh, int nb4,
                            const float* __restrict__ c, half_t* __restrict__ ch, int nc4) {
    int i = blockIdx.x * blockDim.x + threadIdx.x;
    const float* src;
    half_t* dst;
    int j = i;
    if (j < na4) { src = a; dst = ah; }
    else if ((j -= na4) < nb4) { src = b; dst = bh; }
    else if ((j -= nb4) < nc4) { src = c; dst = ch; }
    else return;
    float4 v = ((const float4*)src)[j];
    half4 o;
    o.x = (half_t)v.x; o.y = (half_t)v.y; o.z = (half_t)v.z; o.w = (half_t)v.w;
    ((half4*)dst)[j] = o;
}

// ---------------- fp16 propagation hop: dst[v] = sum_e w_e * src[row_e] ----------------
// 32-lane group per node, 8 nodes per 256-thread block; 4-deep unroll, 4 accumulators.
__global__ __launch_bounds__(256) void prop16_kernel(const half_t* __restrict__ src,
                                                     half_t* __restrict__ dst,
                                                     const int* __restrict__ offs,
                                                     const int2* __restrict__ csr, int N) {
    int v = blockIdx.x * 8 + (threadIdx.x >> 5);
    if (v >= N) return;
    int lane = threadIdx.x & 31;
    int s0 = offs[v];
    int s1 = offs[v + 1];
    float4v a0 = (float4v)0.0f, a1 = (float4v)0.0f, a2 = (float4v)0.0f, a3 = (float4v)0.0f;
    int i = s0;
    for (; i + 3 < s1; i += 4) {
        int2 e0 = csr[i], e1 = csr[i + 1], e2 = csr[i + 2], e3 = csr[i + 3];
        half4 v0 = *(const half4*)(src + (size_t)e0.x * FEAT + lane * 4);
        half4 v1 = *(const half4*)(src + (size_t)e1.x * FEAT + lane * 4);
        half4 v2 = *(const half4*)(src + (size_t)e2.x * FEAT + lane * 4);
        half4 v3 = *(const half4*)(src + (size_t)e3.x * FEAT + lane * 4);
        float w0 = __int_as_float(e0.y), w1 = __int_as_float(e1.y);
        float w2 = __int_as_float(e2.y), w3 = __int_as_float(e3.y);
        a0.x = fmaf(w0, (float)v0.x, a0.x); a0.y = fmaf(w0, (float)v0.y, a0.y);
        a0.z = fmaf(w0, (float)v0.z, a0.z); a0.w = fmaf(w0, (float)v0.w, a0.w);
        a1.x = fmaf(w1, (float)v1.x, a1.x); a1.y = fmaf(w1, (float)v1.y, a1.y);
        a1.z = fmaf(w1, (float)v1.z, a1.z); a1.w = fmaf(w1, (float)v1.w, a1.w);
        a2.x = fmaf(w2, (float)v2.x, a2.x); a2.y = fmaf(w2, (float)v2.y, a2.y);
        a2.z = fmaf(w2, (float)v2.z, a2.z); a2.w = fmaf(w2, (float)v2.w, a2.w);
        a3.x = fmaf(w3, (float)v3.x, a3.x); a3.y = fmaf(w3, (float)v3.y, a3.y);
        a3.z = fmaf(w3, (float)v3.z, a3.z); a3.w = fmaf(w3, (float)v3.w, a3.w);
    }
    for (; i < s1; ++i) {
        int2 e0 = csr[i];
        float w0 = __int_as_float(e0.y);
        half4 v0 = *(const half4*)(src + (size_t)e0.x * FEAT + lane * 4);
        a0.x = fmaf(w0, (float)v0.x, a0.x); a0.y = fmaf(w0, (float)v0.y, a0.y);
        a0.z = fmaf(w0, (float)v0.z, a0.z); a0.w = fmaf(w0, (float)v0.w, a0.w);
    }
    half4 o;
    o.x = (half_t)((a0.x + a1.x) + (a2.x + a3.x));
    o.y = (half_t)((a0.y + a1.y) + (a2.y + a3.y));
    o.z = (half_t)((a0.z + a1.z) + (a2.z + a3.z));
    o.w = (half_t)((a0.w + a1.w) + (a2.w + a3.w));
    *(half4*)(dst + (size_t)v * FEAT + lane * 4) = o;
}

// ---------------- MFMA GEMM: out[M,128] = concat(H0..H3)[M,512] @ W[128,512].T + b ----------------
template <bool RELU, bool HALFOUT>
__global__ __launch_bounds__(256) void gemm16_kernel(const half_t* __restrict__ H0,
                                                     const half_t* __restrict__ H1,
                                                     const half_t* __restrict__ H2,
                                                     const half_t* __restrict__ H3,
                                                     const half_t* __restrict__ W,   // [128][512] fp16
                                                     const float* __restrict__ bias, // [128] fp32
                                                     half_t* __restrict__ out_h,
                                                     float* __restrict__ out_f, int N) {
    __shared__ half_t ws[128][40];   // [o][k-slice 32, pad->40]
    const int tid = threadIdx.x;
    const int lane = tid & 63;
    const int wid = tid >> 6;
    const int lr = lane & 15;        // m-in-tile
    const int lk = lane >> 4;        // 0..3
    const int m = blockIdx.x * 64 + wid * 16 + lr;
    const bool mok = (m < N);

    float4v acc[8];
#pragma unroll
    for (int ct = 0; ct < 8; ++ct) acc[ct] = (float4v)0.0f;

    const half_t* Hs[4] = {H0, H1, H2, H3};
    const int wo = tid >> 1;
    const int wh = tid & 1;

#pragma unroll
    for (int b = 0; b < 4; ++b) {
        const half_t* __restrict__ H = Hs[b];
#pragma unroll
        for (int kt = 0; kt < 128; kt += 32) {
            half8 hfrag = (half8)(half_t)0.0f;
            if (mok) hfrag = *(const half8*)(H + (size_t)m * FEAT + kt + lk * 8);
            const half8* wsrc = (const half8*)(W + (size_t)wo * 512 + b * 128 + kt + wh * 16);
            half8 w0 = wsrc[0];
            half8 w1 = wsrc[1];
            __syncthreads();
            *(half8*)&ws[wo][wh * 16 + 0] = w0;
            *(half8*)&ws[wo][wh * 16 + 8] = w1;
            __syncthreads();
#pragma unroll
            for (int ct = 0; ct < 8; ++ct) {
                half8 wfrag = *(const half8*)&ws[ct * 16 + lr][lk * 8];
                acc[ct] = __builtin_amdgcn_mfma_f32_16x16x32_f16(wfrag, hfrag, acc[ct], 0, 0, 0);
            }
        }
    }

    if (mok) {
#pragma unroll
        for (int ct = 0; ct < 8; ++ct) {
            int o = ct * 16 + lk * 4;
            float4 bv = *(const float4*)(bias + o);
            float r0 = acc[ct][0] + bv.x;
            float r1 = acc[ct][1] + bv.y;
            float r2 = acc[ct][2] + bv.z;
            float r3 = acc[ct][3] + bv.w;
            if (RELU) {
                r0 = fmaxf(r0, 0.0f); r1 = fmaxf(r1, 0.0f);
                r2 = fmaxf(r2, 0.0f); r3 = fmaxf(r3, 0.0f);
            }
            if (HALFOUT) {
                half4 hv;
                hv.x = (half_t)r0; hv.y = (half_t)r1; hv.z = (half_t)r2; hv.w = (half_t)r3;
                *(half4*)(out_h + (size_t)m * FEAT + o) = hv;
            } else {
                float4 fv;
                fv.x = r0; fv.y = r1; fv.z = r2; fv.w = r3;
                *(float4*)(out_f + (size_t)m * FEAT + o) = fv;
            }
        }
    }
}

extern "C" void kernel_launch(void* const* d_in, const int* in_sizes, int n_in,
                              void* d_out, int out_size, void* d_ws, size_t ws_size,
                              hipStream_t stream) {
    const float* x   = (const float*)d_in[0];
    const int*   ei  = (const int*)d_in[1];
    const float* W1  = (const float*)d_in[2];
    const float* b1  = (const float*)d_in[3];
    const float* W2  = (const float*)d_in[4];
    const float* b2  = (const float*)d_in[5];
    float* out = (float*)d_out;

    const int N = in_sizes[0] / FEAT;       // 100000
    const int E = in_sizes[1] / 2;          // 1600000
    const int* row = ei;
    const int* col = ei + E;
    const int nb = (N + SCAN_CHUNK - 1) / SCAN_CHUNK;

    // workspace carve
    size_t off = 0;
    auto carve = [&](size_t bytes) -> void* {
        void* p = (char*)d_ws + off;
        off += (bytes + 255) & ~(size_t)255;
        return p;
    };
    int*    deg      = (int*)carve((size_t)N * 4);
    int*    cursor   = (int*)carve((size_t)N * 4);
    float*  dinv     = (float*)carve((size_t)N * 4);
    int*    offs     = (int*)carve((size_t)(N + 1) * 4);
    int*    partials = (int*)carve((size_t)nb * 4);
    int2*   csr      = (int2*)carve((size_t)E * 8);
    half_t* x16      = (half_t*)carve((size_t)N * FEAT * 2);
    half_t* t1       = (half_t*)carve((size_t)N * FEAT * 2);
    half_t* t2       = (half_t*)carve((size_t)N * FEAT * 2);
    half_t* t3       = (half_t*)carve((size_t)N * FEAT * 2);
    half_t* hbuf     = (half_t*)carve((size_t)N * FEAT * 2);
    half_t* w1h      = (half_t*)carve((size_t)FEAT * 512 * 2);
    half_t* w2h      = (half_t*)carve((size_t)FEAT * 512 * 2);

    const int tB = 256;
    const int gE = (E + tB - 1) / tB;
    const int gP = (N + 7) / 8;                 // prop16 blocks (8 nodes/block)
    const int gG = (N + 63) / 64;               // gemm16 blocks (64 rows/block)
    const int xt4 = N * FEAT / 4;
    const int wt4 = FEAT * 512 / 4;
    const int cvt_total = xt4 + 2 * wt4;

    // ---- norm + CSR build ----
    hipMemsetAsync(deg, 0, (size_t)N * 4, stream);
    count_kernel<<<gE, tB, 0, stream>>>(col, deg, E);
    scan_partial_kernel<<<nb, 256, 0, stream>>>(deg, partials, N);
    scan_top_kernel<<<1, 1024, 0, stream>>>(partials, nb, offs + N);
    scan_final_kernel<<<nb, 256, 0, stream>>>(deg, partials, offs, dinv, N);
    hipMemcpyAsync(cursor, offs, (size_t)N * 4, hipMemcpyDeviceToDevice, stream);
    fill_kernel<<<gE, tB, 0, stream>>>(row, col, dinv, cursor, csr, E);

    // ---- fp16 conversions (fused) ----
    f2h3_kernel<<<(cvt_total + tB - 1) / tB, tB, 0, stream>>>(x, x16, xt4, W1, w1h, wt4, W2, w2h, wt4);

    // ---- layer 1: hbuf = relu(concat(x,h1,h2,h3) @ W1.T + b1)  (fp16) ----
    prop16_kernel<<<gP, 256, 0, stream>>>(x16, t1, offs, csr, N);
    prop16_kernel<<<gP, 256, 0, stream>>>(t1, t2, offs, csr, N);
    prop16_kernel<<<gP, 256, 0, stream>>>(t2, t3, offs, csr, N);
    gemm16_kernel<true, true><<<gG, 256, 0, stream>>>(x16, t1, t2, t3, w1h, b1, hbuf, nullptr, N);

    // ---- layer 2: out = concat(hbuf,h1,h2,h3) @ W2.T + b2  (fp32 out) ----
    prop16_kernel<<<gP, 256, 0, stream>>>(hbuf, t1, offs, csr, N);
    prop16_kernel<<<gP, 256, 0, stream>>>(t1, t2, offs, csr, N);
    prop16_kernel<<<gP, 256, 0, stream>>>(t2, t3, offs, csr, N);
    gemm16_kernel<false, false><<<gG, 256, 0, stream>>>(hbuf, t1, t2, t3, w2h, b2, nullptr, out, N);
}